// Round 1
// baseline (80.030 us; speedup 1.0000x reference)
//
#include <hip/hip_runtime.h>
#include <math.h>

#define NB 16
#define NL 4096
#define NC 512
#define NC4 128          // NC/4 float4 per row
#define NKEEP 2458       // ceil(4096*0.6)

// ---------------- ws layout ----------------
// key   : u64  [NB][NL]   @ 0         (512 KB)
// rank  : int  [NB][NL]   @ 524288    (256 KB)
// wnorm : f32  [NB][NL]   @ 786432    (256 KB)
// alpha : f32  [NB]       @ 1048576
// beta  : f32  [NB]       @ 1048576+64

// Kernel 1: bit-exact replica of np.float32 pairwise mean (PW_BLOCKSIZE=128,
// 8-accumulator base case, balanced binary combine == butterfly), then
// coverage/sigmoid. One wave per batch; lanes 0..31 own 128-elem base blocks.
__global__ void __launch_bounds__(64) k_alpha(const float* __restrict__ ax,
                                              const float* __restrict__ ay,
                                              float* __restrict__ alpha,
                                              float* __restrict__ beta) {
  int b = blockIdx.x;
  int lane = threadIdx.x;
  float sx = 0.0f, sy = 0.0f;
  if (lane < 32) {
    const float* px = ax + b * NL + lane * 128;
    const float* py = ay + b * NL + lane * 128;
    float r[8], q[8];
#pragma unroll
    for (int j = 0; j < 8; ++j) { r[j] = px[j]; q[j] = py[j]; }
    for (int i = 8; i < 128; i += 8) {
#pragma unroll
      for (int j = 0; j < 8; ++j) {
        r[j] = __fadd_rn(r[j], px[i + j]);
        q[j] = __fadd_rn(q[j], py[i + j]);
      }
    }
    sx = __fadd_rn(__fadd_rn(__fadd_rn(r[0], r[1]), __fadd_rn(r[2], r[3])),
                   __fadd_rn(__fadd_rn(r[4], r[5]), __fadd_rn(r[6], r[7])));
    sy = __fadd_rn(__fadd_rn(__fadd_rn(q[0], q[1]), __fadd_rn(q[2], q[3])),
                   __fadd_rn(__fadd_rn(q[4], q[5]), __fadd_rn(q[6], q[7])));
  }
  // balanced-tree combine over 32 leaves (matches np recursive halving exactly;
  // f32 add is commutative so xor-butterfly association == np association)
#pragma unroll
  for (int m = 1; m <= 16; m <<= 1) {
    sx = __fadd_rn(sx, __shfl_xor(sx, m, 64));
    sy = __fadd_rn(sy, __shfl_xor(sy, m, 64));
  }
  if (lane == 0) {
    float mx = __fdiv_rn(sx, 4096.0f);   // np: sum / n  (exact pow2 scale)
    float my = __fdiv_rn(sy, 4096.0f);
    float cov = __fdiv_rn(my, __fadd_rn(mx, 1e-6f));
    float z = __fsub_rn(1.0f, cov);
    double a = 1.0 / (1.0 + exp(-(double)z));   // correctly-rounded sigmoid
    float af = (float)a;
    alpha[b] = af;
    beta[b] = __fsub_rn(1.0f, af);
  }
}

// Kernel 2: composite sort keys. score with mul,mul,add (no FMA) to match np.
__global__ void __launch_bounds__(256) k_keys(const float* __restrict__ ax,
                                              const float* __restrict__ ay,
                                              const float* __restrict__ alpha,
                                              const float* __restrict__ beta,
                                              unsigned long long* __restrict__ key,
                                              int* __restrict__ rank) {
  int idx = blockIdx.x * 256 + threadIdx.x;   // 65536
  int b = idx >> 12;
  int l = idx & (NL - 1);
  float s = __fadd_rn(__fmul_rn(alpha[b], ax[idx]), __fmul_rn(beta[b], ay[idx]));
  unsigned u = __float_as_uint(s);
  unsigned su = u ^ ((u & 0x80000000u) ? 0xFFFFFFFFu : 0x80000000u); // ascending map
  unsigned du = ~su;                                                 // descending
  key[idx] = ((unsigned long long)du << 32) | (unsigned)l;           // stable tiebreak
  rank[idx] = 0;
}

// Kernel 3: rank(i) = #{j : key_j < key_i}. grid (ichunk, jchunk, batch).
__global__ void __launch_bounds__(256) k_rank(const unsigned long long* __restrict__ key,
                                              int* __restrict__ rank) {
  __shared__ unsigned long long tile[256];
  int b = blockIdx.z;
  int i = blockIdx.x * 256 + threadIdx.x;
  const unsigned long long* kb = key + b * NL;
  unsigned long long ki = kb[i];
  int j0 = blockIdx.y * 512;
  int cnt = 0;
  for (int jt = 0; jt < 512; jt += 256) {
    __syncthreads();
    tile[threadIdx.x] = kb[j0 + jt + threadIdx.x];
    __syncthreads();
#pragma unroll 16
    for (int jj = 0; jj < 256; ++jj) cnt += (tile[jj] < ki) ? 1 : 0;
  }
  atomicAdd(&rank[b * NL + i], cnt);   // int atomics: exact, deterministic
}

// Kernel 4: per-batch finalize: mask, softmax max m (= score of rank NKEEP),
// Z, normalized weights. One block per batch.
__global__ void __launch_bounds__(1024) k_final(const float* __restrict__ ax,
                                                const float* __restrict__ ay,
                                                const float* __restrict__ alpha,
                                                const float* __restrict__ beta,
                                                const int* __restrict__ rank,
                                                float* __restrict__ wnorm,
                                                float* __restrict__ mask_out) {
  int b = blockIdx.x;
  int tid = threadIdx.x;
  __shared__ float sm;
  __shared__ float red[1024];
  float s[4];
  int r[4];
  float af = alpha[b], bf = beta[b];
#pragma unroll
  for (int p = 0; p < 4; ++p) {
    int idx = b * NL + p * 1024 + tid;
    r[p] = rank[idx];
    s[p] = __fadd_rn(__fmul_rn(af, ax[idx]), __fmul_rn(bf, ay[idx]));
    mask_out[idx] = (r[p] < NKEEP) ? 1.0f : 0.0f;
    if (r[p] == NKEEP) sm = s[p];   // exactly one element has this rank
  }
  __syncthreads();
  float m = sm;
  float w[4];
  float part = 0.0f;
#pragma unroll
  for (int p = 0; p < 4; ++p) {
    w[p] = (r[p] >= NKEEP) ? expf(s[p] - m) : 0.0f;
    part += w[p];
  }
  red[tid] = part;
  __syncthreads();
  for (int off = 512; off > 0; off >>= 1) {
    if (tid < off) red[tid] += red[tid + off];
    __syncthreads();
  }
  float invZ = 1.0f / red[0];
#pragma unroll
  for (int p = 0; p < 4; ++p) {
    int idx = b * NL + p * 1024 + tid;
    wnorm[idx] = w[p] * invZ;
  }
}

// Kernel 5: row gather (rank < NKEEP -> select[rank]) + weighted accumulation
// of non-keep rows into extra (float atomics; |noise| ~1e-6 << threshold).
__global__ void __launch_bounds__(128) k_gather(const float4* __restrict__ tok,
                                                const int* __restrict__ rank,
                                                const float* __restrict__ wnorm,
                                                float4* __restrict__ sel,
                                                float* __restrict__ extra) {
  int b = blockIdx.y;
  int t = threadIdx.x;          // float4 column 0..127
  int row0 = blockIdx.x * 32;   // 128 chunks of 32 rows
  float accx = 0.f, accy = 0.f, accz = 0.f, accw = 0.f;
  for (int rr = 0; rr < 32; ++rr) {
    int idx = b * NL + row0 + rr;
    int r = rank[idx];
    float4 v = tok[(size_t)idx * NC4 + t];
    if (r < NKEEP) {
      sel[((size_t)b * NKEEP + r) * NC4 + t] = v;
    } else {
      float w = wnorm[idx];
      accx = fmaf(w, v.x, accx);
      accy = fmaf(w, v.y, accy);
      accz = fmaf(w, v.z, accz);
      accw = fmaf(w, v.w, accw);
    }
  }
  float* e = extra + b * NC + t * 4;
  atomicAdd(e + 0, accx);
  atomicAdd(e + 1, accy);
  atomicAdd(e + 2, accz);
  atomicAdd(e + 3, accw);
}

extern "C" void kernel_launch(void* const* d_in, const int* in_sizes, int n_in,
                              void* d_out, int out_size, void* d_ws, size_t ws_size,
                              hipStream_t stream) {
  (void)in_sizes; (void)n_in; (void)out_size; (void)ws_size;
  const float4* tok = (const float4*)d_in[0];
  const float* ax = (const float*)d_in[1];
  const float* ay = (const float*)d_in[2];

  unsigned long long* key = (unsigned long long*)d_ws;
  int* rank = (int*)((char*)d_ws + 524288);
  float* wnorm = (float*)((char*)d_ws + 786432);
  float* alpha = (float*)((char*)d_ws + 1048576);
  float* beta = alpha + 16;

  float* out = (float*)d_out;
  float4* sel = (float4*)out;                       // [16][2458][512]
  float* extra = out + (size_t)NB * NKEEP * NC;     // [16][1][512]
  float* mask = extra + (size_t)NB * NC;            // [16][4096]

  hipMemsetAsync(extra, 0, (size_t)NB * NC * sizeof(float), stream);

  k_alpha<<<NB, 64, 0, stream>>>(ax, ay, alpha, beta);
  k_keys<<<256, 256, 0, stream>>>(ax, ay, alpha, beta, key, rank);
  k_rank<<<dim3(16, 8, NB), 256, 0, stream>>>(key, rank);
  k_final<<<NB, 1024, 0, stream>>>(ax, ay, alpha, beta, rank, wnorm, mask);
  k_gather<<<dim3(128, NB), 128, 0, stream>>>(tok, rank, wnorm, sel, extra);
}